// Round 1
// baseline (602.739 us; speedup 1.0000x reference)
//
#include <hip/hip_runtime.h>
#include <stdint.h>

// Problem constants
#define BATCH   32768
#define F_IN    64
#define HID     32
#define E_LEN   25
#define N_G     12
#define N_H     8
#define N_HG    96           // H*G
#define BN_EPS  1e-5f

// ws layout (bytes)
#define WS_P1   0            // 128*32 f32 partial sums
#define WS_P2   16384        // 128*32 f32 partial sumsq
#define WS_SS   32768        // 64 f32: scale[32], shift[32]
#define WS_WT   33024        // 96*25*32 f16  (153600 B), read as u32 pairs
#define WS_EQ   186624       // 32768*16 u32 packed f16 e-rows (2 MB)

typedef _Float16 half2_t __attribute__((ext_vector_type(2)));

__device__ __forceinline__ float selu_f(float x) {
    const float lam = 1.0507009873554805f;
    const float la  = 1.7580993408473766f;   // lam * alpha
    return x > 0.f ? lam * x : la * (__expf(x) - 1.f);
}

__device__ __forceinline__ float dot2f(uint32_t w, uint32_t e, float acc) {
    return __builtin_amdgcn_fdot2(__builtin_bit_cast(half2_t, w),
                                  __builtin_bit_cast(half2_t, e), acc, false);
}

// Shared feature extractor up to h2 (pre-BN). One row per thread.
__device__ __forceinline__ void compute_h2(const float* __restrict__ xr,
                                           const float* __restrict__ W1,
                                           const float* __restrict__ b1,
                                           const float* __restrict__ W2,
                                           const float* __restrict__ b2,
                                           float h2[HID]) {
    float x[F_IN];
    const float4* x4 = (const float4*)xr;
#pragma unroll
    for (int i = 0; i < F_IN / 4; ++i) {
        float4 v = x4[i];
        x[4*i] = v.x; x[4*i+1] = v.y; x[4*i+2] = v.z; x[4*i+3] = v.w;
    }
    float h[HID];
#pragma unroll
    for (int j = 0; j < HID; ++j) h[j] = b1[j];
#pragma unroll 4
    for (int i = 0; i < F_IN; ++i) {
        float xi = x[i];
#pragma unroll
        for (int j = 0; j < HID; ++j) h[j] = fmaf(xi, W1[i*HID + j], h[j]);
    }
#pragma unroll
    for (int j = 0; j < HID; ++j) h[j] = selu_f(h[j]);
#pragma unroll
    for (int j = 0; j < HID; ++j) h2[j] = b2[j];
#pragma unroll 4
    for (int k = 0; k < HID; ++k) {
        float hk = h[k];
#pragma unroll
        for (int j = 0; j < HID; ++j) h2[j] = fmaf(hk, W2[k*HID + j], h2[j]);
    }
}

// K0: Wh [96][32][25] f32  ->  wt16 [96][25][32] f16  (dot2-pair friendly)
__global__ __launch_bounds__(256) void k0_weights(const float* __restrict__ Wh,
                                                  uint16_t* __restrict__ wt16) {
    int t = blockIdx.x * 256 + threadIdx.x;
    if (t >= N_HG * E_LEN * HID) return;
    int hg = t / (E_LEN * HID);
    int r  = t % (E_LEN * HID);
    int ee = r / HID;
    int f  = r % HID;
    float v = Wh[hg * (HID * E_LEN) + f * E_LEN + ee];
    _Float16 hv = (_Float16)v;
    wt16[t] = __builtin_bit_cast(uint16_t, hv);
}

// K1: batch stats partials (sum, sumsq) per feature per block of 256 rows.
__global__ __launch_bounds__(256) void k1_stats(const float* __restrict__ inp,
                                                const float* __restrict__ W1,
                                                const float* __restrict__ b1,
                                                const float* __restrict__ W2,
                                                const float* __restrict__ b2,
                                                float* __restrict__ p1,
                                                float* __restrict__ p2) {
    __shared__ float l1[4][HID];
    __shared__ float l2[4][HID];
    int row  = blockIdx.x * 256 + threadIdx.x;
    int lane = threadIdx.x & 63;
    int wave = threadIdx.x >> 6;

    float h2[HID];
    compute_h2(inp + (size_t)row * F_IN, W1, b1, W2, b2, h2);

#pragma unroll
    for (int j = 0; j < HID; ++j) {
        float a = h2[j];
        float b = h2[j] * h2[j];
#pragma unroll
        for (int off = 32; off > 0; off >>= 1) {
            a += __shfl_xor(a, off, 64);
            b += __shfl_xor(b, off, 64);
        }
        if (lane == 0) { l1[wave][j] = a; l2[wave][j] = b; }
    }
    __syncthreads();
    if (threadIdx.x < HID) {
        int f = threadIdx.x;
        float a = l1[0][f] + l1[1][f] + l1[2][f] + l1[3][f];
        float b = l2[0][f] + l2[1][f] + l2[2][f] + l2[3][f];
        p1[blockIdx.x * HID + f] = a;
        p2[blockIdx.x * HID + f] = b;
    }
}

// K2: fold 128 partials -> scale/shift per feature.
__global__ __launch_bounds__(256) void k2_fold(const float* __restrict__ p1,
                                               const float* __restrict__ p2,
                                               const float* __restrict__ gamma,
                                               const float* __restrict__ beta,
                                               float* __restrict__ ss) {
    __shared__ float l1[8][HID];
    __shared__ float l2[8][HID];
    int f = threadIdx.x & 31;
    int c = threadIdx.x >> 5;
    float a = 0.f, b = 0.f;
    for (int i = c; i < 128; i += 8) {
        a += p1[i * HID + f];
        b += p2[i * HID + f];
    }
    l1[c][f] = a; l2[c][f] = b;
    __syncthreads();
    if (threadIdx.x < HID) {
        float A = 0.f, Bv = 0.f;
#pragma unroll
        for (int i = 0; i < 8; ++i) { A += l1[i][f]; Bv += l2[i][f]; }
        float mu  = A * (1.0f / (float)BATCH);
        float var = Bv * (1.0f / (float)BATCH) - mu * mu;
        float sc  = gamma[f] * rsqrtf(var + BN_EPS);
        ss[f]        = sc;
        ss[HID + f]  = beta[f] - mu * sc;
    }
}

// K3: recompute h2, BN affine, SELU, pack to f16 pairs.
__global__ __launch_bounds__(256) void k3_efeat(const float* __restrict__ inp,
                                                const float* __restrict__ W1,
                                                const float* __restrict__ b1,
                                                const float* __restrict__ W2,
                                                const float* __restrict__ b2,
                                                const float* __restrict__ ss,
                                                uint32_t* __restrict__ eq) {
    int row = blockIdx.x * 256 + threadIdx.x;
    float h2[HID];
    compute_h2(inp + (size_t)row * F_IN, W1, b1, W2, b2, h2);
    uint32_t packed[HID / 2];
#pragma unroll
    for (int k = 0; k < HID / 2; ++k) {
        float e0 = selu_f(fmaf(h2[2*k],   ss[2*k],   ss[HID + 2*k]));
        float e1 = selu_f(fmaf(h2[2*k+1], ss[2*k+1], ss[HID + 2*k+1]));
        half2_t p;
        p[0] = (_Float16)e0;
        p[1] = (_Float16)e1;
        packed[k] = __builtin_bit_cast(uint32_t, p);
    }
    uint4* dst = (uint4*)(eq + (size_t)row * (HID / 2));
#pragma unroll
    for (int k = 0; k < 4; ++k)
        dst[k] = make_uint4(packed[4*k], packed[4*k+1], packed[4*k+2], packed[4*k+3]);
}

// K4: heads GEMM + SELU + L1 normalize. thread = row; blockIdx.y = segment of 12 groups.
__global__ __launch_bounds__(256) void k4_heads(const uint32_t* __restrict__ eq,
                                                const uint32_t* __restrict__ wt,
                                                const float* __restrict__ bh,
                                                float* __restrict__ out) {
    int row = blockIdx.x * 256 + threadIdx.x;
    int seg = blockIdx.y;                       // 0..7, 12 groups each

    uint32_t e2[HID / 2];
    const uint4* ep = (const uint4*)(eq + (size_t)row * (HID / 2));
#pragma unroll
    for (int k = 0; k < 4; ++k) {
        uint4 v = ep[k];
        e2[4*k] = v.x; e2[4*k+1] = v.y; e2[4*k+2] = v.z; e2[4*k+3] = v.w;
    }

    float* outr = out + (size_t)row * (N_HG * E_LEN) + seg * (12 * E_LEN);

    for (int gi = 0; gi < 12; ++gi) {
        int hg = seg * 12 + gi;
        const uint32_t* w   = wt + hg * (E_LEN * HID / 2);   // uniform address
        const float*    bia = bh + hg * E_LEN;               // uniform address

        float d[E_LEN];
        float l1 = 0.f;
#pragma unroll
        for (int ee = 0; ee < E_LEN; ++ee) {
            float acc = bia[ee];
#pragma unroll
            for (int k = 0; k < HID / 2; ++k)
                acc = dot2f(w[ee * (HID / 2) + k], e2[k], acc);
            float dv = selu_f(acc);
            d[ee] = dv;
            l1 += fabsf(dv);
        }
        float inv = 1.0f / fmaxf(l1, 1e-12f);
        float* o = outr + gi * E_LEN;
#pragma unroll
        for (int ee = 0; ee < E_LEN; ++ee)
            o[ee] = d[ee] * inv;
    }
}

extern "C" void kernel_launch(void* const* d_in, const int* in_sizes, int n_in,
                              void* d_out, int out_size, void* d_ws, size_t ws_size,
                              hipStream_t stream) {
    const float* inp   = (const float*)d_in[0];
    const float* W1    = (const float*)d_in[1];
    const float* b1    = (const float*)d_in[2];
    const float* W2    = (const float*)d_in[3];
    const float* b2    = (const float*)d_in[4];
    const float* gamma = (const float*)d_in[5];
    const float* beta  = (const float*)d_in[6];
    const float* Wh    = (const float*)d_in[7];
    const float* bh    = (const float*)d_in[8];
    float* out = (float*)d_out;

    char* ws = (char*)d_ws;
    float*    p1   = (float*)(ws + WS_P1);
    float*    p2   = (float*)(ws + WS_P2);
    float*    ss   = (float*)(ws + WS_SS);
    uint16_t* wt16 = (uint16_t*)(ws + WS_WT);
    uint32_t* wtq  = (uint32_t*)(ws + WS_WT);
    uint32_t* eq   = (uint32_t*)(ws + WS_EQ);

    hipLaunchKernelGGL(k0_weights, dim3(300), dim3(256), 0, stream, Wh, wt16);
    hipLaunchKernelGGL(k1_stats,   dim3(128), dim3(256), 0, stream, inp, W1, b1, W2, b2, p1, p2);
    hipLaunchKernelGGL(k2_fold,    dim3(1),   dim3(256), 0, stream, p1, p2, gamma, beta, ss);
    hipLaunchKernelGGL(k3_efeat,   dim3(128), dim3(256), 0, stream, inp, W1, b1, W2, b2, ss, eq);
    hipLaunchKernelGGL(k4_heads,   dim3(128, 8), dim3(256), 0, stream, eq, wtq, bh, out);
}

// Round 2
// 591.516 us; speedup vs baseline: 1.0190x; 1.0190x over previous
//
#include <hip/hip_runtime.h>
#include <stdint.h>

// Problem constants
#define BATCH   32768
#define F_IN    64
#define HID     32
#define E_LEN   25
#define N_HG    96           // H*G
#define BN_EPS  1e-5f

#define NBLK1   512          // k1 blocks (64 threads each, 1 row/thread)

// ws layout (bytes)
#define WS_WT   0            // 96*25*32 f16 = 153600 B (u32-paired)
#define WS_P1   153600       // 512*32 f32 partial sums      (65536)
#define WS_P2   219136       // 512*32 f32 partial sumsq     (65536)
#define WS_SS   284672       // 64 f32: scale[32], shift[32]
#define WS_H2   284928       // 32768*32 f32 h2 rows (4 MB)

typedef _Float16 half2_t __attribute__((ext_vector_type(2)));

__device__ __forceinline__ float selu_f(float x) {
    const float lam = 1.0507009873554805f;
    const float la  = 1.7580993408473766f;   // lam * alpha
    return x > 0.f ? lam * x : la * (__expf(x) - 1.f);
}

__device__ __forceinline__ float dot2f(uint32_t w, uint32_t e, float acc) {
    return __builtin_amdgcn_fdot2(__builtin_bit_cast(half2_t, w),
                                  __builtin_bit_cast(half2_t, e), acc, false);
}

// Shared feature extractor up to h2 (pre-BN). One row per thread.
__device__ __forceinline__ void compute_h2(const float* __restrict__ xr,
                                           const float* __restrict__ W1,
                                           const float* __restrict__ b1,
                                           const float* __restrict__ W2,
                                           const float* __restrict__ b2,
                                           float h2[HID]) {
    float x[F_IN];
    const float4* x4 = (const float4*)xr;
#pragma unroll
    for (int i = 0; i < F_IN / 4; ++i) {
        float4 v = x4[i];
        x[4*i] = v.x; x[4*i+1] = v.y; x[4*i+2] = v.z; x[4*i+3] = v.w;
    }
    float h[HID];
#pragma unroll
    for (int j = 0; j < HID; ++j) h[j] = b1[j];
#pragma unroll 4
    for (int i = 0; i < F_IN; ++i) {
        float xi = x[i];
#pragma unroll
        for (int j = 0; j < HID; ++j) h[j] = fmaf(xi, W1[i*HID + j], h[j]);
    }
#pragma unroll
    for (int j = 0; j < HID; ++j) h[j] = selu_f(h[j]);
#pragma unroll
    for (int j = 0; j < HID; ++j) h2[j] = b2[j];
#pragma unroll 4
    for (int k = 0; k < HID; ++k) {
        float hk = h[k];
#pragma unroll
        for (int j = 0; j < HID; ++j) h2[j] = fmaf(hk, W2[k*HID + j], h2[j]);
    }
}

// K0: Wh [96][32][25] f32  ->  wt16 [96][25][32] f16  (dot2-pair friendly)
__global__ __launch_bounds__(256) void k0_weights(const float* __restrict__ Wh,
                                                  uint16_t* __restrict__ wt16) {
    int t = blockIdx.x * 256 + threadIdx.x;
    if (t >= N_HG * E_LEN * HID) return;
    int hg = t / (E_LEN * HID);
    int r  = t % (E_LEN * HID);
    int ee = r / HID;
    int f  = r % HID;
    float v = Wh[hg * (HID * E_LEN) + f * E_LEN + ee];
    _Float16 hv = (_Float16)v;
    wt16[t] = __builtin_bit_cast(uint16_t, hv);
}

// K1: compute h2, store it, emit per-block (sum, sumsq) partials. 64 thr/blk.
__global__ __launch_bounds__(64) void k1_stats(const float* __restrict__ inp,
                                               const float* __restrict__ W1,
                                               const float* __restrict__ b1,
                                               const float* __restrict__ W2,
                                               const float* __restrict__ b2,
                                               float* __restrict__ h2out,
                                               float* __restrict__ p1,
                                               float* __restrict__ p2) {
    int row  = blockIdx.x * 64 + threadIdx.x;
    int lane = threadIdx.x;

    float h2[HID];
    compute_h2(inp + (size_t)row * F_IN, W1, b1, W2, b2, h2);

    float4* dst = (float4*)(h2out + (size_t)row * HID);
#pragma unroll
    for (int k = 0; k < HID / 4; ++k)
        dst[k] = make_float4(h2[4*k], h2[4*k+1], h2[4*k+2], h2[4*k+3]);

#pragma unroll
    for (int j = 0; j < HID; ++j) {
        float a = h2[j];
        float b = h2[j] * h2[j];
#pragma unroll
        for (int off = 32; off > 0; off >>= 1) {
            a += __shfl_xor(a, off, 64);
            b += __shfl_xor(b, off, 64);
        }
        if (lane == 0) { p1[blockIdx.x * HID + j] = a; p2[blockIdx.x * HID + j] = b; }
    }
}

// K2: fold NBLK1 partials -> scale/shift per feature.
__global__ __launch_bounds__(256) void k2_fold(const float* __restrict__ p1,
                                               const float* __restrict__ p2,
                                               const float* __restrict__ gamma,
                                               const float* __restrict__ beta,
                                               float* __restrict__ ss) {
    __shared__ float l1[8][HID];
    __shared__ float l2[8][HID];
    int f = threadIdx.x & 31;
    int c = threadIdx.x >> 5;
    float a = 0.f, b = 0.f;
    for (int i = c; i < NBLK1; i += 8) {
        a += p1[i * HID + f];
        b += p2[i * HID + f];
    }
    l1[c][f] = a; l2[c][f] = b;
    __syncthreads();
    if (threadIdx.x < HID) {
        float A = 0.f, Bv = 0.f;
#pragma unroll
        for (int i = 0; i < 8; ++i) { A += l1[i][f]; Bv += l2[i][f]; }
        float mu  = A * (1.0f / (float)BATCH);
        float var = Bv * (1.0f / (float)BATCH) - mu * mu;
        float sc  = gamma[f] * rsqrtf(var + BN_EPS);
        ss[f]        = sc;
        ss[HID + f]  = beta[f] - mu * sc;
    }
}

// K4: BN+SELU (e), heads GEMM + SELU + L1 normalize, LDS-transposed coalesced
// stores. Block = 256 thr = 4 waves over the SAME 64 rows (lane<->row so the
// head weights stay wave-uniform -> SGPR operands). 12 chunks of 8 groups;
// per chunk each wave computes 2 groups, stages normalized values into a
// 64 x 200 f32 tile (stride 201: stage-write banks (9*lane)%32, conflict-free),
// then the whole block flushes the tile as lane-consecutive float4 stores
// (800 B contiguous per row -> full-line writes, no RMW).
#define TROWS 64
#define TSTR  201            // LDS row stride in f32 (odd -> conflict-free stage)

__global__ __launch_bounds__(256) void k4_heads(const float* __restrict__ h2buf,
                                                const float* __restrict__ ss,
                                                const uint32_t* __restrict__ wt,
                                                const float* __restrict__ bh,
                                                float* __restrict__ out) {
    __shared__ float tile[TROWS * TSTR];    // 51456 B

    int lane = threadIdx.x & 63;
    int wave = threadIdx.x >> 6;            // 0..3
    int r0   = blockIdx.x * TROWS;
    int row  = r0 + lane;

    // Build packed f16 e-row in registers: e = selu(h2*scale + shift)
    uint32_t e2[HID / 2];
    {
        const float4* hp = (const float4*)(h2buf + (size_t)row * HID);
#pragma unroll
        for (int k = 0; k < HID / 4; ++k) {
            float4 v = hp[k];
            float e0 = selu_f(fmaf(v.x, ss[4*k+0], ss[HID + 4*k+0]));
            float e1 = selu_f(fmaf(v.y, ss[4*k+1], ss[HID + 4*k+1]));
            float e2v = selu_f(fmaf(v.z, ss[4*k+2], ss[HID + 4*k+2]));
            float e3 = selu_f(fmaf(v.w, ss[4*k+3], ss[HID + 4*k+3]));
            half2_t p0; p0[0] = (_Float16)e0; p0[1] = (_Float16)e1;
            half2_t p1; p1[0] = (_Float16)e2v; p1[1] = (_Float16)e3;
            e2[2*k]   = __builtin_bit_cast(uint32_t, p0);
            e2[2*k+1] = __builtin_bit_cast(uint32_t, p1);
        }
    }

    for (int c = 0; c < 12; ++c) {          // 12 chunks x 8 groups
#pragma unroll
        for (int gs = 0; gs < 2; ++gs) {
            int g  = wave * 2 + gs;         // local group 0..7
            int hg = c * 8 + g;
            const uint32_t* w   = wt + hg * (E_LEN * HID / 2);  // uniform
            const float*    bia = bh + hg * E_LEN;              // uniform

            float d[E_LEN];
            float l1 = 0.f;
#pragma unroll
            for (int ee = 0; ee < E_LEN; ++ee) {
                float acc = bia[ee];
#pragma unroll
                for (int k = 0; k < HID / 2; ++k)
                    acc = dot2f(w[ee * (HID / 2) + k], e2[k], acc);
                float dv = selu_f(acc);
                d[ee] = dv;
                l1 += fabsf(dv);
            }
            float inv = 1.0f / fmaxf(l1, 1e-12f);
            float* t = &tile[lane * TSTR + g * E_LEN];
#pragma unroll
            for (int ee = 0; ee < E_LEN; ++ee)
                t[ee] = d[ee] * inv;
        }
        __syncthreads();

        // flush: 64 rows x 200 f32 = 3200 float4, lane-consecutive
        float* ob = out + (size_t)r0 * (N_HG * E_LEN) + c * 200;
        for (int f4 = threadIdx.x; f4 < 3200; f4 += 256) {
            int rr = f4 / 50;               // 50 float4 per row-chunk
            int w4 = f4 % 50;
            const float* src = &tile[rr * TSTR + w4 * 4];
            float4 v;
            v.x = src[0]; v.y = src[1]; v.z = src[2]; v.w = src[3];
            *(float4*)(ob + (size_t)rr * (N_HG * E_LEN) + w4 * 4) = v;
        }
        __syncthreads();
    }
}

extern "C" void kernel_launch(void* const* d_in, const int* in_sizes, int n_in,
                              void* d_out, int out_size, void* d_ws, size_t ws_size,
                              hipStream_t stream) {
    const float* inp   = (const float*)d_in[0];
    const float* W1    = (const float*)d_in[1];
    const float* b1    = (const float*)d_in[2];
    const float* W2    = (const float*)d_in[3];
    const float* b2    = (const float*)d_in[4];
    const float* gamma = (const float*)d_in[5];
    const float* beta  = (const float*)d_in[6];
    const float* Wh    = (const float*)d_in[7];
    const float* bh    = (const float*)d_in[8];
    float* out = (float*)d_out;

    char* ws = (char*)d_ws;
    uint16_t* wt16 = (uint16_t*)(ws + WS_WT);
    uint32_t* wtq  = (uint32_t*)(ws + WS_WT);
    float*    p1   = (float*)(ws + WS_P1);
    float*    p2   = (float*)(ws + WS_P2);
    float*    ssb  = (float*)(ws + WS_SS);
    float*    h2b  = (float*)(ws + WS_H2);

    hipLaunchKernelGGL(k0_weights, dim3(300),   dim3(256), 0, stream, Wh, wt16);
    hipLaunchKernelGGL(k1_stats,   dim3(NBLK1), dim3(64),  0, stream, inp, W1, b1, W2, b2, h2b, p1, p2);
    hipLaunchKernelGGL(k2_fold,    dim3(1),     dim3(256), 0, stream, p1, p2, gamma, beta, ssb);
    hipLaunchKernelGGL(k4_heads,   dim3(BATCH / TROWS), dim3(256), 0, stream, h2b, ssb, wtq, bh, out);
}